// Round 4
// baseline (114.551 us; speedup 1.0000x reference)
//
#include <hip/hip_runtime.h>
#include <math.h>

// out[b,s,e] = sum_q cos(x[b,s,q] + theta[q]) * W[e,q]
// B=4, S=4096, E=1024, Q=8  -> tokens = 16384
// Memory-bound on the 67 MB output write. Output (67 MB) < Infinity Cache
// (256 MB): NORMAL write-back stores let L2/L3 absorb the stream (async
// drain to HBM is off the critical path). R3's nontemporal stores forced
// the HBM path and regressed -- reverted.

#define E_DIM 1024
#define Q_DIM 8
#define TPB 256
#define TOK_PER_BLOCK 8

__global__ __launch_bounds__(TPB) void quantum_proj_kernel(
    const float* __restrict__ x,      // [tokens, 1024]
    const float* __restrict__ theta,  // [8]
    const float* __restrict__ W,      // [1024, 8]
    float* __restrict__ out,          // [tokens, 1024]
    int tokens)
{
    __shared__ float P[TOK_PER_BLOCK * Q_DIM];   // 256 B

    const int t    = threadIdx.x;
    const int tok0 = blockIdx.x * TOK_PER_BLOCK;
    const bool full = (tok0 + TOK_PER_BLOCK) <= tokens;   // always true for 16384/8

    // ---- Load this thread's 4 W rows (e = 4t .. 4t+3), 32 contiguous floats.
    // Issued first so the VMEM loads overlap the cos phase. W is 32 KB -> L2-hot.
    const int e0 = t * 4;
    float4 wa[4], wb[4];
    {
        const float4* W4 = (const float4*)W;
        #pragma unroll
        for (int i = 0; i < 4; ++i) {
            wa[i] = W4[(size_t)(e0 + i) * 2 + 0];
            wb[i] = W4[(size_t)(e0 + i) * 2 + 1];
        }
    }

    // ---- Phase 1: threads 0..63 compute cos(x[tok][q] + theta[q]) into LDS
    if (t < TOK_PER_BLOCK * Q_DIM) {
        const int tl  = t >> 3;    // local token
        const int q   = t & 7;
        const int tok = tok0 + tl;
        float v = 0.0f;
        if (tok < tokens) {
            v = cosf(x[(size_t)tok * E_DIM + q] + theta[q]);
        }
        P[t] = v;
    }

    __syncthreads();

    // ---- Phase 2: per token, 32 FMAs + one float4 store
    // (256 lanes x 16 B = 4 KB contiguous per token; 32 KB contiguous/block)
    if (full) {
        #pragma unroll
        for (int tl = 0; tl < TOK_PER_BLOCK; ++tl) {
            const int tok = tok0 + tl;

            float p[Q_DIM];
            #pragma unroll
            for (int q = 0; q < Q_DIM; ++q) p[q] = P[tl * Q_DIM + q];  // LDS broadcast

            float4 acc;
            acc.x = p[0]*wa[0].x; acc.y = p[0]*wa[1].x;
            acc.z = p[0]*wa[2].x; acc.w = p[0]*wa[3].x;
            acc.x = fmaf(p[1], wa[0].y, acc.x); acc.y = fmaf(p[1], wa[1].y, acc.y);
            acc.z = fmaf(p[1], wa[2].y, acc.z); acc.w = fmaf(p[1], wa[3].y, acc.w);
            acc.x = fmaf(p[2], wa[0].z, acc.x); acc.y = fmaf(p[2], wa[1].z, acc.y);
            acc.z = fmaf(p[2], wa[2].z, acc.z); acc.w = fmaf(p[2], wa[3].z, acc.w);
            acc.x = fmaf(p[3], wa[0].w, acc.x); acc.y = fmaf(p[3], wa[1].w, acc.y);
            acc.z = fmaf(p[3], wa[2].w, acc.z); acc.w = fmaf(p[3], wa[3].w, acc.w);
            acc.x = fmaf(p[4], wb[0].x, acc.x); acc.y = fmaf(p[4], wb[1].x, acc.y);
            acc.z = fmaf(p[4], wb[2].x, acc.z); acc.w = fmaf(p[4], wb[3].x, acc.w);
            acc.x = fmaf(p[5], wb[0].y, acc.x); acc.y = fmaf(p[5], wb[1].y, acc.y);
            acc.z = fmaf(p[5], wb[2].y, acc.z); acc.w = fmaf(p[5], wb[3].y, acc.w);
            acc.x = fmaf(p[6], wb[0].z, acc.x); acc.y = fmaf(p[6], wb[1].z, acc.y);
            acc.z = fmaf(p[6], wb[2].z, acc.z); acc.w = fmaf(p[6], wb[3].z, acc.w);
            acc.x = fmaf(p[7], wb[0].w, acc.x); acc.y = fmaf(p[7], wb[1].w, acc.y);
            acc.z = fmaf(p[7], wb[2].w, acc.z); acc.w = fmaf(p[7], wb[3].w, acc.w);

            float4* op = (float4*)(out + (size_t)tok * E_DIM) + t;
            *op = acc;
        }
    } else {
        for (int tl = 0; tl < TOK_PER_BLOCK; ++tl) {
            const int tok = tok0 + tl;
            if (tok >= tokens) break;
            float p[Q_DIM];
            for (int q = 0; q < Q_DIM; ++q) p[q] = P[tl * Q_DIM + q];
            float acc[4] = {0.f, 0.f, 0.f, 0.f};
            const float* wrow = (const float*)wa;  // not used in tail path; recompute simply
            (void)wrow;
            float wf[4][Q_DIM];
            #pragma unroll
            for (int i = 0; i < 4; ++i) {
                wf[i][0]=wa[i].x; wf[i][1]=wa[i].y; wf[i][2]=wa[i].z; wf[i][3]=wa[i].w;
                wf[i][4]=wb[i].x; wf[i][5]=wb[i].y; wf[i][6]=wb[i].z; wf[i][7]=wb[i].w;
            }
            for (int i = 0; i < 4; ++i)
                for (int q = 0; q < Q_DIM; ++q)
                    acc[i] = fmaf(p[q], wf[i][q], acc[i]);
            float4* op = (float4*)(out + (size_t)tok * E_DIM) + t;
            *op = make_float4(acc[0], acc[1], acc[2], acc[3]);
        }
    }
}

extern "C" void kernel_launch(void* const* d_in, const int* in_sizes, int n_in,
                              void* d_out, int out_size, void* d_ws, size_t ws_size,
                              hipStream_t stream) {
    const float* x     = (const float*)d_in[0];
    const float* theta = (const float*)d_in[1];
    const float* W     = (const float*)d_in[2];
    float* out = (float*)d_out;

    const int tokens = in_sizes[0] / E_DIM;            // 16384
    const int grid   = (tokens + TOK_PER_BLOCK - 1) / TOK_PER_BLOCK;  // 2048

    quantum_proj_kernel<<<dim3(grid), dim3(TPB), 0, stream>>>(x, theta, W, out, tokens);
}

// Round 5
// 110.149 us; speedup vs baseline: 1.0400x; 1.0400x over previous
//
#include <hip/hip_runtime.h>
#include <math.h>

// out[b,s,e] = sum_q cos(x[b,s,q] + theta[q]) * W[e,q]
// B=4, S=4096, E=1024, Q=8  -> tokens = 16384
// Memory-bound on the 67 MB output write; write floor ~11 us at 6.3 TB/s.
// R5: best-measured config (16 tok/block, 1024 blocks = 4/CU; halves per-block
// W reload traffic vs 8 tok/block) + float4 LDS reads (2x ds_read_b128/token
// instead of 8x ds_read_b32) + plain cached stores (L3 absorbs the stream;
// nontemporal regressed in R3).

#define E_DIM 1024
#define Q_DIM 8
#define TPB 256
#define TOK_PER_BLOCK 16

__global__ __launch_bounds__(TPB) void quantum_proj_kernel(
    const float* __restrict__ x,      // [tokens, 1024]
    const float* __restrict__ theta,  // [8]
    const float* __restrict__ W,      // [1024, 8]
    float* __restrict__ out,          // [tokens, 1024]
    int tokens)
{
    __shared__ float4 P[TOK_PER_BLOCK * 2];   // [tok][2] float4 halves, 512 B

    const int t    = threadIdx.x;
    const int tok0 = blockIdx.x * TOK_PER_BLOCK;

    // ---- W preload: thread t owns output columns e = 4t..4t+3 (32 contiguous
    // floats = 128 B, coalesced dwordx4). Issued first to overlap phase 1.
    const int e0 = t * 4;
    float4 wa[4], wb[4];
    {
        const float4* W4 = (const float4*)W;
        #pragma unroll
        for (int i = 0; i < 4; ++i) {
            wa[i] = W4[(size_t)(e0 + i) * 2 + 0];
            wb[i] = W4[(size_t)(e0 + i) * 2 + 1];
        }
    }

    // ---- Phase 1: threads 0..127 compute cos(x[tok][q] + theta[q]) into LDS
    if (t < TOK_PER_BLOCK * Q_DIM) {
        const int tl  = t >> 3;    // local token
        const int q   = t & 7;
        const int tok = tok0 + tl;
        float v = 0.0f;
        if (tok < tokens) {
            v = cosf(x[(size_t)tok * E_DIM + q] + theta[q]);
        }
        ((float*)P)[t] = v;
    }

    __syncthreads();

    const bool full = (tok0 + TOK_PER_BLOCK) <= tokens;  // true for all 1024 blocks at 16384

    if (full) {
        // ---- Phase 2: per token, 2 ds_read_b128 + 32 FMAs + 1 float4 store
        // (256 lanes x 16 B = 4 KB contiguous per token)
        #pragma unroll
        for (int tl = 0; tl < TOK_PER_BLOCK; ++tl) {
            const float4 pl = P[tl * 2 + 0];   // p[0..3], LDS broadcast
            const float4 ph = P[tl * 2 + 1];   // p[4..7]

            float4 acc;
            acc.x = pl.x * wa[0].x; acc.y = pl.x * wa[1].x;
            acc.z = pl.x * wa[2].x; acc.w = pl.x * wa[3].x;
            acc.x = fmaf(pl.y, wa[0].y, acc.x); acc.y = fmaf(pl.y, wa[1].y, acc.y);
            acc.z = fmaf(pl.y, wa[2].y, acc.z); acc.w = fmaf(pl.y, wa[3].y, acc.w);
            acc.x = fmaf(pl.z, wa[0].z, acc.x); acc.y = fmaf(pl.z, wa[1].z, acc.y);
            acc.z = fmaf(pl.z, wa[2].z, acc.z); acc.w = fmaf(pl.z, wa[3].z, acc.w);
            acc.x = fmaf(pl.w, wa[0].w, acc.x); acc.y = fmaf(pl.w, wa[1].w, acc.y);
            acc.z = fmaf(pl.w, wa[2].w, acc.z); acc.w = fmaf(pl.w, wa[3].w, acc.w);
            acc.x = fmaf(ph.x, wb[0].x, acc.x); acc.y = fmaf(ph.x, wb[1].x, acc.y);
            acc.z = fmaf(ph.x, wb[2].x, acc.z); acc.w = fmaf(ph.x, wb[3].x, acc.w);
            acc.x = fmaf(ph.y, wb[0].y, acc.x); acc.y = fmaf(ph.y, wb[1].y, acc.y);
            acc.z = fmaf(ph.y, wb[2].y, acc.z); acc.w = fmaf(ph.y, wb[3].y, acc.w);
            acc.x = fmaf(ph.z, wb[0].z, acc.x); acc.y = fmaf(ph.z, wb[1].z, acc.y);
            acc.z = fmaf(ph.z, wb[2].z, acc.z); acc.w = fmaf(ph.z, wb[3].z, acc.w);
            acc.x = fmaf(ph.w, wb[0].w, acc.x); acc.y = fmaf(ph.w, wb[1].w, acc.y);
            acc.z = fmaf(ph.w, wb[2].w, acc.z); acc.w = fmaf(ph.w, wb[3].w, acc.w);

            float4* op = (float4*)(out + (size_t)(tok0 + tl) * E_DIM) + t;
            *op = acc;
        }
    } else {
        // Generic tail (unused at 16384 tokens)
        for (int tl = 0; tl < TOK_PER_BLOCK; ++tl) {
            const int tok = tok0 + tl;
            if (tok >= tokens) break;
            const float* p = (const float*)&P[tl * 2];
            float wf[4][Q_DIM];
            #pragma unroll
            for (int i = 0; i < 4; ++i) {
                wf[i][0]=wa[i].x; wf[i][1]=wa[i].y; wf[i][2]=wa[i].z; wf[i][3]=wa[i].w;
                wf[i][4]=wb[i].x; wf[i][5]=wb[i].y; wf[i][6]=wb[i].z; wf[i][7]=wb[i].w;
            }
            float acc[4] = {0.f, 0.f, 0.f, 0.f};
            for (int i = 0; i < 4; ++i)
                for (int q = 0; q < Q_DIM; ++q)
                    acc[i] = fmaf(p[q], wf[i][q], acc[i]);
            float4* op = (float4*)(out + (size_t)tok * E_DIM) + t;
            *op = make_float4(acc[0], acc[1], acc[2], acc[3]);
        }
    }
}

extern "C" void kernel_launch(void* const* d_in, const int* in_sizes, int n_in,
                              void* d_out, int out_size, void* d_ws, size_t ws_size,
                              hipStream_t stream) {
    const float* x     = (const float*)d_in[0];
    const float* theta = (const float*)d_in[1];
    const float* W     = (const float*)d_in[2];
    float* out = (float*)d_out;

    const int tokens = in_sizes[0] / E_DIM;            // 16384
    const int grid   = (tokens + TOK_PER_BLOCK - 1) / TOK_PER_BLOCK;  // 1024

    quantum_proj_kernel<<<dim3(grid), dim3(TPB), 0, stream>>>(x, theta, W, out, tokens);
}